// Round 9
// baseline (1026.617 us; speedup 1.0000x reference)
//
#include <hip/hip_runtime.h>
#include <math.h>

#define NROWS 10000
#define FEAT  512
#define NHID  64
#define NCLS  10
#define YT_STRIDE 10240   // 10000 padded (zeros in pad); stored XOR-swizzled
#define KB_PAD 320        // padded K blocks of 32 (for dyn fallback)
#define TK    64          // gemm_adj K-tile
#define NSPLIT 5
#define NT    32          // tiles per split = 10240 / TK / NSPLIT

typedef __attribute__((ext_vector_type(8))) short short8;
typedef __attribute__((ext_vector_type(4))) float f32x4;

__device__ __forceinline__ short f2bf(float f) {
  union { float f; unsigned u; } v; v.f = f;
  unsigned r = v.u + 0x7fffu + ((v.u >> 16) & 1u);
  return (short)(r >> 16);
}

__device__ __forceinline__ float wsum64(float v) {
#pragma unroll
  for (int off = 32; off > 0; off >>= 1) v += __shfl_xor(v, off, 64);
  return v;
}

// async global->LDS, 16B per lane, LDS dest = wave-uniform base + lane*16.
__device__ __forceinline__ void gload16(const void* g, void* l) {
  __builtin_amdgcn_global_load_lds(
      (const __attribute__((address_space(1))) unsigned int*)g,
      (__attribute__((address_space(3))) unsigned int*)l, 16, 0, 0);
}

// ---------------------------------------------------------------------------
__global__ __launch_bounds__(256) void prep_w(const float* __restrict__ W1,
                                              const float* __restrict__ W2,
                                              unsigned short* __restrict__ Wt1,
                                              unsigned short* __restrict__ Wt2) {
  int i = blockIdx.x * 256 + threadIdx.x;
  if (i >= FEAT * NHID) return;
  int k = i >> 6, h = i & 63;
  Wt1[h * FEAT + k] = (unsigned short)f2bf(W1[i]);
  Wt2[h * FEAT + k] = (unsigned short)f2bf(W2[i]);
}

// ---------------------------------------------------------------------------
// Kernel 1: Yt_b[col][row^sw(col)] = bf16((x @ W_b)[row][col]), sw(c)=(c&7)<<3.
__global__ __launch_bounds__(256) void gemm_xw(const float* __restrict__ x,
                                               const unsigned short* __restrict__ Wt1,
                                               const unsigned short* __restrict__ Wt2,
                                               unsigned short* __restrict__ Yt1,
                                               unsigned short* __restrict__ Yt2) {
  const int lane = threadIdx.x & 63;
  const int wave = threadIdx.x >> 6;
  const int job = blockIdx.x * 4 + wave;
  if (job >= 1250) return;
  const int br = (job >= 625) ? 1 : 0;
  const int tile = job - 625 * br;
  const unsigned short* Wt = br ? Wt2 : Wt1;
  unsigned short* Yt       = br ? Yt2 : Yt1;
  const int rowbase = tile * 16;
  const int r16 = lane & 15, g = lane >> 4, ga = g * 8;

  const float* arow = x + (size_t)(rowbase + r16) * FEAT + ga;
  const unsigned short* bp = Wt + (size_t)r16 * FEAT + ga;

  f32x4 acc[4];
#pragma unroll
  for (int t = 0; t < 4; ++t) acc[t] = (f32x4){0.f, 0.f, 0.f, 0.f};

#pragma unroll
  for (int kb = 0; kb < FEAT / 32; ++kb) {
    const int k0 = kb * 32;
    const f32x4* ap = (const f32x4*)(arow + k0);
    f32x4 a0 = ap[0], a1 = ap[1];
    short8 af;
    af[0] = f2bf(a0[0]); af[1] = f2bf(a0[1]); af[2] = f2bf(a0[2]); af[3] = f2bf(a0[3]);
    af[4] = f2bf(a1[0]); af[5] = f2bf(a1[1]); af[6] = f2bf(a1[2]); af[7] = f2bf(a1[3]);
#pragma unroll
    for (int t = 0; t < 4; ++t) {
      short8 bf = *(const short8*)(bp + (size_t)t * 16 * FEAT + k0);
      acc[t] = __builtin_amdgcn_mfma_f32_16x16x32_bf16(af, bf, acc[t], 0, 0, 0);
    }
  }
  const int sw = (r16 & 7) << 3;
#pragma unroll
  for (int t = 0; t < 4; ++t)
#pragma unroll
    for (int rr = 0; rr < 4; ++rr) {
      const int col = t * 16 + r16;
      const int row = rowbase + g * 4 + rr;
      Yt[(size_t)col * YT_STRIDE + (row ^ sw)] = (unsigned short)f2bf(acc[t][rr]);
    }
}

// ---------------------------------------------------------------------------
// Kernel 2 (carrier, EXACTLY R8): E = adj @ Y, 64x64xTK=64 tile, A+B LDS ring.
__global__ __launch_bounds__(256, 3) void gemm_adj(const float* __restrict__ adj1,
                                                   const float* __restrict__ adj2,
                                                   const unsigned short* __restrict__ Yt1,
                                                   const unsigned short* __restrict__ Yt2,
                                                   float* __restrict__ Ep) {
  __shared__ __attribute__((aligned(16))) float          Asm[2][64 * TK];
  __shared__ __attribute__((aligned(16))) unsigned short Bsm[2][64 * TK];

  const int sp = blockIdx.y;
  const int br = blockIdx.z;
  const float* adj         = br ? adj2 : adj1;
  const unsigned short* Yt = br ? Yt2 : Yt1;
  float* E = Ep + (size_t)(br * NSPLIT + sp) * NROWS * NHID;
  const int k_base = sp * (NT * TK);
  const int blockrow = blockIdx.x * 64;

  const int lane = threadIdx.x & 63;
  const int wave = threadIdx.x >> 6;

  const int a_rt_l = (lane >> 4);
  const int a_gran = (lane & 15) * 4;
  const int b_cl = lane >> 3;
  const int b_el = (lane & 7) * 8;

  const int wr = wave >> 1, wc = wave & 1;
  const int r16 = lane & 15, g = lane >> 4;
  const int aswz = (r16 & 7) << 2;
  const int swb  = (r16 & 7) << 3;

  f32x4 acc00 = (f32x4){0.f, 0.f, 0.f, 0.f};
  f32x4 acc01 = acc00, acc10 = acc00, acc11 = acc00;

#define STAGE(tt) { const int k0s = k_base + (tt) * TK; const int bufs = (tt) & 1;   \
    _Pragma("unroll")                                                                 \
    for (int j = 0; j < 4; ++j) {                                                     \
      const int rt = wave * 16 + j * 4 + a_rt_l;                                      \
      const int gr = min(blockrow + rt, NROWS - 1);                                   \
      const int fsrc = a_gran ^ ((rt & 7) << 2);                                      \
      const float* asrc = adj + (size_t)gr * NROWS + min(k0s + fsrc, NROWS - 4);      \
      gload16(asrc, &Asm[bufs][(wave * 16 + j * 4) * TK]);                            \
    }                                                                                 \
    _Pragma("unroll")                                                                 \
    for (int j = 0; j < 2; ++j) {                                                     \
      const int c0 = wave * 16 + j * 8;                                               \
      const unsigned short* bsrc =                                                    \
          Yt + (size_t)(c0 + b_cl) * YT_STRIDE + (k0s + b_el);                        \
      gload16(bsrc, &Bsm[bufs][c0 * TK]);                                             \
    } }

#define COMPUTE(tt) { const int bufc = (tt) & 1;                                      \
    _Pragma("unroll")                                                                 \
    for (int ks = 0; ks < 2; ++ks) {                                                  \
      const int kx = ks * 32 + g * 8;                                                 \
      const float* ab0 = &Asm[bufc][(wr * 32 + r16) * TK];                            \
      const float* ab1 = &Asm[bufc][(wr * 32 + 16 + r16) * TK];                       \
      f32x4 a00 = *(const f32x4*)(ab0 + (kx ^ aswz));                                 \
      f32x4 a01 = *(const f32x4*)(ab0 + ((kx + 4) ^ aswz));                           \
      f32x4 a10 = *(const f32x4*)(ab1 + (kx ^ aswz));                                 \
      f32x4 a11 = *(const f32x4*)(ab1 + ((kx + 4) ^ aswz));                           \
      short8 b0 = *(const short8*)&Bsm[bufc][(wc * 32 + r16) * TK + (kx ^ swb)];      \
      short8 b1 = *(const short8*)&Bsm[bufc][(wc * 32 + 16 + r16) * TK + (kx ^ swb)]; \
      short8 af0, af1;                                                                \
      af0[0] = f2bf(a00[0]); af0[1] = f2bf(a00[1]); af0[2] = f2bf(a00[2]);            \
      af0[3] = f2bf(a00[3]); af0[4] = f2bf(a01[0]); af0[5] = f2bf(a01[1]);            \
      af0[6] = f2bf(a01[2]); af0[7] = f2bf(a01[3]);                                   \
      af1[0] = f2bf(a10[0]); af1[1] = f2bf(a10[1]); af1[2] = f2bf(a10[2]);            \
      af1[3] = f2bf(a10[3]); af1[4] = f2bf(a11[0]); af1[5] = f2bf(a11[1]);            \
      af1[6] = f2bf(a11[2]); af1[7] = f2bf(a11[3]);                                   \
      acc00 = __builtin_amdgcn_mfma_f32_16x16x32_bf16(af0, b0, acc00, 0, 0, 0);       \
      acc01 = __builtin_amdgcn_mfma_f32_16x16x32_bf16(af0, b1, acc01, 0, 0, 0);       \
      acc10 = __builtin_amdgcn_mfma_f32_16x16x32_bf16(af1, b0, acc10, 0, 0, 0);       \
      acc11 = __builtin_amdgcn_mfma_f32_16x16x32_bf16(af1, b1, acc11, 0, 0, 0);       \
    } }

  STAGE(0);
#pragma unroll 2
  for (int t = 0; t < NT - 1; ++t) {
    STAGE(t + 1);
    asm volatile("s_waitcnt vmcnt(6)" ::: "memory");
    __builtin_amdgcn_sched_barrier(0);
    __builtin_amdgcn_s_barrier();
    __builtin_amdgcn_sched_barrier(0);
    COMPUTE(t);
    __builtin_amdgcn_s_barrier();
  }
  asm volatile("s_waitcnt vmcnt(0)" ::: "memory");
  __builtin_amdgcn_sched_barrier(0);
  __builtin_amdgcn_s_barrier();
  __builtin_amdgcn_sched_barrier(0);
  COMPUTE(NT - 1);
#undef STAGE
#undef COMPUTE

#pragma unroll
  for (int rr = 0; rr < 4; ++rr) {
    const int grow0 = blockrow + wr * 32 + g * 4 + rr;
    const int grow1 = grow0 + 16;
    const int col   = wc * 32 + r16;
    if (grow0 < NROWS) {
      float* e = E + (size_t)grow0 * NHID + col;
      e[0]  = acc00[rr];
      e[16] = acc01[rr];
    }
    if (grow1 < NROWS) {
      float* e = E + (size_t)grow1 * NHID + col;
      e[0]  = acc10[rr];
      e[16] = acc11[rr];
    }
  }
}

// ---------------------------------------------------------------------------
// PROBE 1: ideal streaming read, 2.4 GB (adj1 + adj2 + adj1 again).
__global__ __launch_bounds__(256) void probe_stream(const float* __restrict__ a1,
                                                    const float* __restrict__ a2,
                                                    float* __restrict__ o) {
  const size_t tid = (size_t)blockIdx.x * 256 + threadIdx.x;
  const size_t stride = (size_t)gridDim.x * 256;
  const size_t n4 = (size_t)NROWS * NROWS / 4;
  f32x4 acc = (f32x4){0.f, 0.f, 0.f, 0.f};
  for (size_t i = tid; i < n4; i += stride) acc += ((const f32x4*)a1)[i];
  for (size_t i = tid; i < n4; i += stride) acc += ((const f32x4*)a2)[i];
  for (size_t i = tid; i < n4; i += stride) acc += ((const f32x4*)a1)[i];
  o[tid] = acc[0] + acc[1] + acc[2] + acc[3];
}

// ---------------------------------------------------------------------------
// PROBE 2: gemm_adj's EXACT staging ring (same grid/LDS/vmcnt/barriers), no
// compute, 2 reps = 2.4 GB staged.  Measures the ring's raw delivery rate.
__global__ __launch_bounds__(256, 3) void probe_ring(const float* __restrict__ adj1,
                                                     const float* __restrict__ adj2,
                                                     const unsigned short* __restrict__ Yt1,
                                                     const unsigned short* __restrict__ Yt2,
                                                     float* __restrict__ o) {
  __shared__ __attribute__((aligned(16))) float          Asm[2][64 * TK];
  __shared__ __attribute__((aligned(16))) unsigned short Bsm[2][64 * TK];

  const int sp = blockIdx.y;
  const int br = blockIdx.z;
  const float* adj         = br ? adj2 : adj1;
  const unsigned short* Yt = br ? Yt2 : Yt1;
  const int k_base = sp * (NT * TK);
  const int blockrow = blockIdx.x * 64;

  const int lane = threadIdx.x & 63;
  const int wave = threadIdx.x >> 6;
  const int a_rt_l = (lane >> 4);
  const int a_gran = (lane & 15) * 4;
  const int b_cl = lane >> 3;
  const int b_el = (lane & 7) * 8;

#define PSTAGE(tt) { const int k0s = k_base + (tt) * TK; const int bufs = (tt) & 1;  \
    _Pragma("unroll")                                                                 \
    for (int j = 0; j < 4; ++j) {                                                     \
      const int rt = wave * 16 + j * 4 + a_rt_l;                                      \
      const int gr = min(blockrow + rt, NROWS - 1);                                   \
      const int fsrc = a_gran ^ ((rt & 7) << 2);                                      \
      const float* asrc = adj + (size_t)gr * NROWS + min(k0s + fsrc, NROWS - 4);      \
      gload16(asrc, &Asm[bufs][(wave * 16 + j * 4) * TK]);                            \
    }                                                                                 \
    _Pragma("unroll")                                                                 \
    for (int j = 0; j < 2; ++j) {                                                     \
      const int c0 = wave * 16 + j * 8;                                               \
      const unsigned short* bsrc =                                                    \
          Yt + (size_t)(c0 + b_cl) * YT_STRIDE + (k0s + b_el);                        \
      gload16(bsrc, &Bsm[bufs][c0 * TK]);                                             \
    } }

  for (int rep = 0; rep < 2; ++rep) {
    PSTAGE(0);
#pragma unroll 2
    for (int t = 0; t < NT - 1; ++t) {
      PSTAGE(t + 1);
      asm volatile("s_waitcnt vmcnt(6)" ::: "memory");
      __builtin_amdgcn_sched_barrier(0);
      __builtin_amdgcn_s_barrier();
      __builtin_amdgcn_s_barrier();
    }
    asm volatile("s_waitcnt vmcnt(0)" ::: "memory");
    __builtin_amdgcn_sched_barrier(0);
    __builtin_amdgcn_s_barrier();
  }
#undef PSTAGE

  float s = Asm[0][threadIdx.x] + (float)Bsm[0][threadIdx.x];
  if (threadIdx.x == 0)
    o[((size_t)blockIdx.z * gridDim.y + blockIdx.y) * gridDim.x + blockIdx.x] = s;
}

// ---------------------------------------------------------------------------
// Fallback (dynamic split) if workspace is tight.  Swizzle-aware B reads.
__global__ __launch_bounds__(256) void gemm_adj_dyn(const float* __restrict__ adj1,
                                                    const float* __restrict__ adj2,
                                                    const unsigned short* __restrict__ Yt1,
                                                    const unsigned short* __restrict__ Yt2,
                                                    float* __restrict__ Ep,
                                                    int nsplit, int chunk) {
  const int sp = blockIdx.y;
  const int br = blockIdx.z;
  const float* adj          = br ? adj2 : adj1;
  const unsigned short* Yt  = br ? Yt2 : Yt1;
  float* E = Ep + (size_t)(br * nsplit + sp) * NROWS * NHID;

  const int kb_begin = sp * chunk;
  const int kb_end   = min(kb_begin + chunk, KB_PAD);

  const int lane = threadIdx.x & 63;
  const int wave = threadIdx.x >> 6;
  const int rowbase = blockIdx.x * 64 + wave * 16;
  if (rowbase >= NROWS) return;
  const int r = lane & 15;
  const int g = lane >> 4;
  const int ga = g * 8;
  const int sw = (r & 7) << 3;

  const float* arow = adj + (size_t)(rowbase + r) * NROWS;

  f32x4 acc0 = (f32x4){0.f, 0.f, 0.f, 0.f};
  f32x4 acc1 = acc0, acc2 = acc0, acc3 = acc0;

#pragma unroll 4
  for (int kb = kb_begin; kb < kb_end; ++kb) {
    const int k0 = kb * 32;
    const int kc = min(k0 + ga, 9992);
    const int ks = (k0 + ga) ^ sw;
    const f32x4* ap = (const f32x4*)(arow + kc);
    f32x4 a0 = ap[0], a1 = ap[1];
    short8 af;
    af[0] = f2bf(a0[0]); af[1] = f2bf(a0[1]); af[2] = f2bf(a0[2]); af[3] = f2bf(a0[3]);
    af[4] = f2bf(a1[0]); af[5] = f2bf(a1[1]); af[6] = f2bf(a1[2]); af[7] = f2bf(a1[3]);
    short8 bf0 = *(const short8*)(Yt + (size_t)(0 * 16 + r) * YT_STRIDE + ks);
    short8 bf1 = *(const short8*)(Yt + (size_t)(1 * 16 + r) * YT_STRIDE + ks);
    short8 bf2 = *(const short8*)(Yt + (size_t)(2 * 16 + r) * YT_STRIDE + ks);
    short8 bf3 = *(const short8*)(Yt + (size_t)(3 * 16 + r) * YT_STRIDE + ks);
    acc0 = __builtin_amdgcn_mfma_f32_16x16x32_bf16(af, bf0, acc0, 0, 0, 0);
    acc1 = __builtin_amdgcn_mfma_f32_16x16x32_bf16(af, bf1, acc1, 0, 0, 0);
    acc2 = __builtin_amdgcn_mfma_f32_16x16x32_bf16(af, bf2, acc2, 0, 0, 0);
    acc3 = __builtin_amdgcn_mfma_f32_16x16x32_bf16(af, bf3, acc3, 0, 0, 0);
  }

  const size_t ebase = (size_t)(rowbase + g * 4) * NHID + r;
#pragma unroll
  for (int rr = 0; rr < 4; ++rr) {
    E[ebase + (size_t)rr * NHID +  0] = acc0[rr];
    E[ebase + (size_t)rr * NHID + 16] = acc1[rr];
    E[ebase + (size_t)rr * NHID + 32] = acc2[rr];
    E[ebase + (size_t)rr * NHID + 48] = acc3[rr];
  }
}

// ---------------------------------------------------------------------------
// Kernel 3: split-K reduction + bias + attention fusion + DEC assignment.
__global__ __launch_bounds__(256) void fuse(const float* __restrict__ Ep,
                                            int nsplit,
                                            const float* __restrict__ b1,
                                            const float* __restrict__ b2,
                                            const float* __restrict__ aw,
                                            const float* __restrict__ cl,
                                            float* __restrict__ out) {
  const int lane = threadIdx.x & 63;
  const int wave = threadIdx.x >> 6;
  const int row = blockIdx.x * 4 + wave;
  if (row >= NROWS) return;

  const size_t off = (size_t)row * NHID + lane;
  const size_t bstride = (size_t)nsplit * NROWS * NHID;
  float e1 = b1[lane], e2 = b2[lane];
  for (int s = 0; s < nsplit; ++s) {
    e1 += Ep[(size_t)s * NROWS * NHID + off];
    e2 += Ep[bstride + (size_t)s * NROWS * NHID + off];
  }

  float a = aw[lane];
  float w1 = wsum64(e1 * a);
  float w2 = wsum64(e2 * a);
  float m = fmaxf(w1, w2);
  float x1 = expf(w1 - m), x2 = expf(w2 - m);
  float inv = 1.0f / (x1 + x2);
  float emb = (x1 * e1 + x2 * e2) * inv;
  out[off] = emb;

  float myq = 0.f, qs = 0.f;
#pragma unroll
  for (int c = 0; c < NCLS; ++c) {
    float d = emb - cl[c * NHID + lane];
    float s = wsum64(d * d);
    float t = exp2f(-0.72f * log2f(fmaf(5.0f, s, 1.0f)));
    qs += t;
    if (lane == c) myq = t;
  }
  if (lane < NCLS) out[(size_t)NROWS * NHID + (size_t)row * NCLS + lane] = myq / qs;
}

// ---------------------------------------------------------------------------
extern "C" void kernel_launch(void* const* d_in, const int* in_sizes, int n_in,
                              void* d_out, int out_size, void* d_ws, size_t ws_size,
                              hipStream_t stream) {
  const float* x    = (const float*)d_in[0];
  const float* adj1 = (const float*)d_in[1];
  const float* adj2 = (const float*)d_in[2];
  const float* W1   = (const float*)d_in[3];
  const float* b1   = (const float*)d_in[4];
  const float* W2   = (const float*)d_in[5];
  const float* b2   = (const float*)d_in[6];
  const float* aw   = (const float*)d_in[7];
  const float* cl   = (const float*)d_in[8];
  float* out = (float*)d_out;

  char* ws = (char*)d_ws;
  unsigned short* Yt1 = (unsigned short*)(ws + 0);        // 64*10240*2 = 1310720
  unsigned short* Yt2 = (unsigned short*)(ws + 1310720);
  unsigned short* Wt1 = (unsigned short*)(ws + 2621440);  // 64*512*2 = 65536
  unsigned short* Wt2 = (unsigned short*)(ws + 2686976);
  float* Ep           = (float*)(ws + 2752512);

  const size_t fixed = 2752512;
  const size_t per_split = 2ull * NROWS * NHID * 4ull;    // both branches: 5.12 MB
  const bool static_ok = ws_size >= fixed + (size_t)NSPLIT * per_split;
  // probe scratch well past Ep (Ep ends ~28.97 MB)
  float* probe_o1 = (float*)(ws + (40ull << 20));
  float* probe_o2 = (float*)(ws + (44ull << 20));
  const bool probes_ok = ws_size >= (48ull << 20);

  hipMemsetAsync(Yt1, 0, 2 * 1310720, stream);
  prep_w<<<dim3(128), dim3(256), 0, stream>>>(W1, W2, Wt1, Wt2);
  gemm_xw<<<dim3(313), dim3(256), 0, stream>>>(x, Wt1, Wt2, Yt1, Yt2);

  if (static_ok) {
    gemm_adj<<<dim3(157, NSPLIT, 2), dim3(256), 0, stream>>>(adj1, adj2, Yt1, Yt2, Ep);
    fuse<<<dim3(2500), dim3(256), 0, stream>>>(Ep, NSPLIT, b1, b2, aw, cl, out);
  } else {
    int nsplit = 1;
    if (ws_size > fixed + per_split) {
      size_t s = (ws_size - fixed) / per_split;
      nsplit = (int)(s < 5 ? s : 5);
      if (nsplit < 1) nsplit = 1;
    }
    const int chunk = (KB_PAD + nsplit - 1) / nsplit;
    gemm_adj_dyn<<<dim3(157, nsplit, 2), dim3(256), 0, stream>>>(adj1, adj2, Yt1, Yt2,
                                                                 Ep, nsplit, chunk);
    fuse<<<dim3(2500), dim3(256), 0, stream>>>(Ep, nsplit, b1, b2, aw, cl, out);
  }

  // ---- diagnostic probes (this round only): run AFTER the real pipeline ----
  if (probes_ok) {
    probe_stream<<<dim3(2048), dim3(256), 0, stream>>>(adj1, adj2, probe_o1);
    probe_ring<<<dim3(157, NSPLIT, 2), dim3(256), 0, stream>>>(adj1, adj2, Yt1, Yt2,
                                                               probe_o2);
  }
}

// Round 10
// 224.009 us; speedup vs baseline: 4.5829x; 4.5829x over previous
//
#include <hip/hip_runtime.h>
#include <math.h>

#define NROWS 10000
#define FEAT  512
#define NHID  64
#define NCLS  10
#define YT_STRIDE 10240   // 10000 padded (zeros in pad); stored XOR-swizzled
#define KB_PAD 320        // padded K blocks of 32 (for dyn fallback)
#define TK    64          // gemm_adj K-tile
#define TM    128         // gemm_adj M-tile (halves B restage vs TM=64)
#define NSPLIT 5
#define NT    32          // tiles per split = 10240 / TK / NSPLIT

typedef __attribute__((ext_vector_type(8))) short short8;
typedef __attribute__((ext_vector_type(4))) float f32x4;

__device__ __forceinline__ short f2bf(float f) {
  union { float f; unsigned u; } v; v.f = f;
  unsigned r = v.u + 0x7fffu + ((v.u >> 16) & 1u);
  return (short)(r >> 16);
}

__device__ __forceinline__ float wsum64(float v) {
#pragma unroll
  for (int off = 32; off > 0; off >>= 1) v += __shfl_xor(v, off, 64);
  return v;
}

// async global->LDS, 16B per lane, LDS dest = wave-uniform base + lane*16.
__device__ __forceinline__ void gload16(const void* g, void* l) {
  __builtin_amdgcn_global_load_lds(
      (const __attribute__((address_space(1))) unsigned int*)g,
      (__attribute__((address_space(3))) unsigned int*)l, 16, 0, 0);
}

// ---------------------------------------------------------------------------
__global__ __launch_bounds__(256) void prep_w(const float* __restrict__ W1,
                                              const float* __restrict__ W2,
                                              unsigned short* __restrict__ Wt1,
                                              unsigned short* __restrict__ Wt2) {
  int i = blockIdx.x * 256 + threadIdx.x;
  if (i >= FEAT * NHID) return;
  int k = i >> 6, h = i & 63;
  Wt1[h * FEAT + k] = (unsigned short)f2bf(W1[i]);
  Wt2[h * FEAT + k] = (unsigned short)f2bf(W2[i]);
}

// ---------------------------------------------------------------------------
// Kernel 1: Yt_b[col][row^sw(col)] = bf16((x @ W_b)[row][col]), sw(c)=(c&7)<<3.
__global__ __launch_bounds__(256) void gemm_xw(const float* __restrict__ x,
                                               const unsigned short* __restrict__ Wt1,
                                               const unsigned short* __restrict__ Wt2,
                                               unsigned short* __restrict__ Yt1,
                                               unsigned short* __restrict__ Yt2) {
  const int lane = threadIdx.x & 63;
  const int wave = threadIdx.x >> 6;
  const int job = blockIdx.x * 4 + wave;
  if (job >= 1250) return;
  const int br = (job >= 625) ? 1 : 0;
  const int tile = job - 625 * br;
  const unsigned short* Wt = br ? Wt2 : Wt1;
  unsigned short* Yt       = br ? Yt2 : Yt1;
  const int rowbase = tile * 16;
  const int r16 = lane & 15, g = lane >> 4, ga = g * 8;

  const float* arow = x + (size_t)(rowbase + r16) * FEAT + ga;
  const unsigned short* bp = Wt + (size_t)r16 * FEAT + ga;

  f32x4 acc[4];
#pragma unroll
  for (int t = 0; t < 4; ++t) acc[t] = (f32x4){0.f, 0.f, 0.f, 0.f};

#pragma unroll
  for (int kb = 0; kb < FEAT / 32; ++kb) {
    const int k0 = kb * 32;
    const f32x4* ap = (const f32x4*)(arow + k0);
    f32x4 a0 = ap[0], a1 = ap[1];
    short8 af;
    af[0] = f2bf(a0[0]); af[1] = f2bf(a0[1]); af[2] = f2bf(a0[2]); af[3] = f2bf(a0[3]);
    af[4] = f2bf(a1[0]); af[5] = f2bf(a1[1]); af[6] = f2bf(a1[2]); af[7] = f2bf(a1[3]);
#pragma unroll
    for (int t = 0; t < 4; ++t) {
      short8 bf = *(const short8*)(bp + (size_t)t * 16 * FEAT + k0);
      acc[t] = __builtin_amdgcn_mfma_f32_16x16x32_bf16(af, bf, acc[t], 0, 0, 0);
    }
  }
  const int sw = (r16 & 7) << 3;
#pragma unroll
  for (int t = 0; t < 4; ++t)
#pragma unroll
    for (int rr = 0; rr < 4; ++rr) {
      const int col = t * 16 + r16;
      const int row = rowbase + g * 4 + rr;
      Yt[(size_t)col * YT_STRIDE + (row ^ sw)] = (unsigned short)f2bf(acc[t][rr]);
    }
}

// ---------------------------------------------------------------------------
// Kernel 2 (the hot one): E = adj @ Y.  TM=128 x 64 cols x TK=64 tile.
// A+B LDS ring via linear global_load_lds (A: per-lane source XOR swizzle;
// B: linear from pre-swizzled Yt).  D=2, 10 stage instrs/wave/tile ->
// vmcnt(10).  LDS 80KB -> 2 blocks/CU.  B restage halved vs TM=64.
__global__ __launch_bounds__(256, 2) void gemm_adj(const float* __restrict__ adj1,
                                                   const float* __restrict__ adj2,
                                                   const unsigned short* __restrict__ Yt1,
                                                   const unsigned short* __restrict__ Yt2,
                                                   float* __restrict__ Ep) {
  __shared__ __attribute__((aligned(16))) float          Asm[2][TM * TK];  // 2x32KB
  __shared__ __attribute__((aligned(16))) unsigned short Bsm[2][64 * TK];  // 2x8KB

  const int sp = blockIdx.y;
  const int br = blockIdx.z;
  const float* adj         = br ? adj2 : adj1;
  const unsigned short* Yt = br ? Yt2 : Yt1;
  float* E = Ep + (size_t)(br * NSPLIT + sp) * NROWS * NHID;
  const int k_base = sp * (NT * TK);
  const int blockrow = blockIdx.x * TM;

  const int lane = threadIdx.x & 63;
  const int wave = threadIdx.x >> 6;

  // ---- A staging: wave stages rows wave*32..+31, 8 instrs x 4 rows ----
  const int a_rt_l = lane >> 4;                      // row within instr (0..3)
  const int a_gran = (lane & 15) * 4;                // float pos (16B granule)
  // ---- B staging: wave stages cols wave*16..+15, 2 instrs x 8 cols ----
  const int b_cl = lane >> 3;                        // col within instr (0..7)
  const int b_el = (lane & 7) * 8;                   // ushort pos in col

  // ---- compute: wave owns rows wave*32..+31, all 64 cols ----
  const int r16 = lane & 15, g = lane >> 4;
  const int aswz = (r16 & 7) << 2;                   // A read xor (floats)
  const int swb  = (r16 & 7) << 3;                   // B read xor (ushorts)

  f32x4 acc0[4], acc1[4];
#pragma unroll
  for (int t = 0; t < 4; ++t) {
    acc0[t] = (f32x4){0.f, 0.f, 0.f, 0.f};
    acc1[t] = (f32x4){0.f, 0.f, 0.f, 0.f};
  }

#define STAGE(tt) { const int k0s = k_base + (tt) * TK; const int bufs = (tt) & 1;   \
    _Pragma("unroll")                                                                 \
    for (int j = 0; j < 8; ++j) {                                                     \
      const int rtb = wave * 32 + j * 4;                                              \
      const int rt = rtb + a_rt_l;                                                    \
      const int gr = min(blockrow + rt, NROWS - 1);                                   \
      const int fsrc = a_gran ^ ((rt & 7) << 2);                                      \
      const float* asrc = adj + (size_t)gr * NROWS + min(k0s + fsrc, NROWS - 4);      \
      gload16(asrc, &Asm[bufs][rtb * TK]);                                            \
    }                                                                                 \
    _Pragma("unroll")                                                                 \
    for (int j = 0; j < 2; ++j) {                                                     \
      const int c0 = wave * 16 + j * 8;                                               \
      const unsigned short* bsrc =                                                    \
          Yt + (size_t)(c0 + b_cl) * YT_STRIDE + (k0s + b_el);                        \
      gload16(bsrc, &Bsm[bufs][c0 * TK]);                                             \
    } }

#define COMPUTE(tt) { const int bufc = (tt) & 1;                                      \
    const float* ab0 = &Asm[bufc][(wave * 32 + r16) * TK];                            \
    const float* ab1 = &Asm[bufc][(wave * 32 + 16 + r16) * TK];                       \
    _Pragma("unroll")                                                                 \
    for (int ks = 0; ks < 2; ++ks) {                                                  \
      const int kx = ks * 32 + g * 8;                                                 \
      f32x4 a00 = *(const f32x4*)(ab0 + (kx ^ aswz));                                 \
      f32x4 a01 = *(const f32x4*)(ab0 + ((kx + 4) ^ aswz));                           \
      f32x4 a10 = *(const f32x4*)(ab1 + (kx ^ aswz));                                 \
      f32x4 a11 = *(const f32x4*)(ab1 + ((kx + 4) ^ aswz));                           \
      short8 af0, af1;                                                                \
      af0[0] = f2bf(a00[0]); af0[1] = f2bf(a00[1]); af0[2] = f2bf(a00[2]);            \
      af0[3] = f2bf(a00[3]); af0[4] = f2bf(a01[0]); af0[5] = f2bf(a01[1]);            \
      af0[6] = f2bf(a01[2]); af0[7] = f2bf(a01[3]);                                   \
      af1[0] = f2bf(a10[0]); af1[1] = f2bf(a10[1]); af1[2] = f2bf(a10[2]);            \
      af1[3] = f2bf(a10[3]); af1[4] = f2bf(a11[0]); af1[5] = f2bf(a11[1]);            \
      af1[6] = f2bf(a11[2]); af1[7] = f2bf(a11[3]);                                   \
      _Pragma("unroll")                                                               \
      for (int ct = 0; ct < 4; ++ct) {                                                \
        short8 b = *(const short8*)&Bsm[bufc][(ct * 16 + r16) * TK + (kx ^ swb)];     \
        acc0[ct] = __builtin_amdgcn_mfma_f32_16x16x32_bf16(af0, b, acc0[ct], 0, 0, 0);\
        acc1[ct] = __builtin_amdgcn_mfma_f32_16x16x32_bf16(af1, b, acc1[ct], 0, 0, 0);\
      }                                                                               \
    } }

  STAGE(0);
#pragma unroll 2
  for (int t = 0; t < NT - 1; ++t) {
    STAGE(t + 1);
    asm volatile("s_waitcnt vmcnt(10)" ::: "memory");  // tile t landed; t+1 flying
    __builtin_amdgcn_sched_barrier(0);
    __builtin_amdgcn_s_barrier();
    __builtin_amdgcn_sched_barrier(0);
    COMPUTE(t);
    __builtin_amdgcn_s_barrier();
  }
  asm volatile("s_waitcnt vmcnt(0)" ::: "memory");
  __builtin_amdgcn_sched_barrier(0);
  __builtin_amdgcn_s_barrier();
  __builtin_amdgcn_sched_barrier(0);
  COMPUTE(NT - 1);
#undef STAGE
#undef COMPUTE

  // C layout per MFMA: col = lane&15, row = (lane>>4)*4 + reg
#pragma unroll
  for (int ct = 0; ct < 4; ++ct)
#pragma unroll
    for (int rr = 0; rr < 4; ++rr) {
      const int grow0 = blockrow + wave * 32 + g * 4 + rr;
      const int grow1 = grow0 + 16;
      const int col   = ct * 16 + r16;
      if (grow0 < NROWS) E[(size_t)grow0 * NHID + col] = acc0[ct][rr];
      if (grow1 < NROWS) E[(size_t)grow1 * NHID + col] = acc1[ct][rr];
    }
}

// ---------------------------------------------------------------------------
// Fallback (dynamic split) if workspace is tight.  Swizzle-aware B reads.
__global__ __launch_bounds__(256) void gemm_adj_dyn(const float* __restrict__ adj1,
                                                    const float* __restrict__ adj2,
                                                    const unsigned short* __restrict__ Yt1,
                                                    const unsigned short* __restrict__ Yt2,
                                                    float* __restrict__ Ep,
                                                    int nsplit, int chunk) {
  const int sp = blockIdx.y;
  const int br = blockIdx.z;
  const float* adj          = br ? adj2 : adj1;
  const unsigned short* Yt  = br ? Yt2 : Yt1;
  float* E = Ep + (size_t)(br * nsplit + sp) * NROWS * NHID;

  const int kb_begin = sp * chunk;
  const int kb_end   = min(kb_begin + chunk, KB_PAD);

  const int lane = threadIdx.x & 63;
  const int wave = threadIdx.x >> 6;
  const int rowbase = blockIdx.x * 64 + wave * 16;
  if (rowbase >= NROWS) return;
  const int r = lane & 15;
  const int g = lane >> 4;
  const int ga = g * 8;
  const int sw = (r & 7) << 3;

  const float* arow = adj + (size_t)(rowbase + r) * NROWS;

  f32x4 acc0 = (f32x4){0.f, 0.f, 0.f, 0.f};
  f32x4 acc1 = acc0, acc2 = acc0, acc3 = acc0;

#pragma unroll 4
  for (int kb = kb_begin; kb < kb_end; ++kb) {
    const int k0 = kb * 32;
    const int kc = min(k0 + ga, 9992);
    const int ks = (k0 + ga) ^ sw;
    const f32x4* ap = (const f32x4*)(arow + kc);
    f32x4 a0 = ap[0], a1 = ap[1];
    short8 af;
    af[0] = f2bf(a0[0]); af[1] = f2bf(a0[1]); af[2] = f2bf(a0[2]); af[3] = f2bf(a0[3]);
    af[4] = f2bf(a1[0]); af[5] = f2bf(a1[1]); af[6] = f2bf(a1[2]); af[7] = f2bf(a1[3]);
    short8 bf0 = *(const short8*)(Yt + (size_t)(0 * 16 + r) * YT_STRIDE + ks);
    short8 bf1 = *(const short8*)(Yt + (size_t)(1 * 16 + r) * YT_STRIDE + ks);
    short8 bf2 = *(const short8*)(Yt + (size_t)(2 * 16 + r) * YT_STRIDE + ks);
    short8 bf3 = *(const short8*)(Yt + (size_t)(3 * 16 + r) * YT_STRIDE + ks);
    acc0 = __builtin_amdgcn_mfma_f32_16x16x32_bf16(af, bf0, acc0, 0, 0, 0);
    acc1 = __builtin_amdgcn_mfma_f32_16x16x32_bf16(af, bf1, acc1, 0, 0, 0);
    acc2 = __builtin_amdgcn_mfma_f32_16x16x32_bf16(af, bf2, acc2, 0, 0, 0);
    acc3 = __builtin_amdgcn_mfma_f32_16x16x32_bf16(af, bf3, acc3, 0, 0, 0);
  }

  const size_t ebase = (size_t)(rowbase + g * 4) * NHID + r;
#pragma unroll
  for (int rr = 0; rr < 4; ++rr) {
    E[ebase + (size_t)rr * NHID +  0] = acc0[rr];
    E[ebase + (size_t)rr * NHID + 16] = acc1[rr];
    E[ebase + (size_t)rr * NHID + 32] = acc2[rr];
    E[ebase + (size_t)rr * NHID + 48] = acc3[rr];
  }
}

// ---------------------------------------------------------------------------
// Kernel 3: split-K reduction + bias + attention fusion + DEC assignment.
__global__ __launch_bounds__(256) void fuse(const float* __restrict__ Ep,
                                            int nsplit,
                                            const float* __restrict__ b1,
                                            const float* __restrict__ b2,
                                            const float* __restrict__ aw,
                                            const float* __restrict__ cl,
                                            float* __restrict__ out) {
  const int lane = threadIdx.x & 63;
  const int wave = threadIdx.x >> 6;
  const int row = blockIdx.x * 4 + wave;
  if (row >= NROWS) return;

  const size_t off = (size_t)row * NHID + lane;
  const size_t bstride = (size_t)nsplit * NROWS * NHID;
  float e1 = b1[lane], e2 = b2[lane];
  for (int s = 0; s < nsplit; ++s) {
    e1 += Ep[(size_t)s * NROWS * NHID + off];
    e2 += Ep[bstride + (size_t)s * NROWS * NHID + off];
  }

  float a = aw[lane];
  float w1 = wsum64(e1 * a);
  float w2 = wsum64(e2 * a);
  float m = fmaxf(w1, w2);
  float x1 = expf(w1 - m), x2 = expf(w2 - m);
  float inv = 1.0f / (x1 + x2);
  float emb = (x1 * e1 + x2 * e2) * inv;
  out[off] = emb;

  float myq = 0.f, qs = 0.f;
#pragma unroll
  for (int c = 0; c < NCLS; ++c) {
    float d = emb - cl[c * NHID + lane];
    float s = wsum64(d * d);
    float t = exp2f(-0.72f * log2f(fmaf(5.0f, s, 1.0f)));
    qs += t;
    if (lane == c) myq = t;
  }
  if (lane < NCLS) out[(size_t)NROWS * NHID + (size_t)row * NCLS + lane] = myq / qs;
}

// ---------------------------------------------------------------------------
extern "C" void kernel_launch(void* const* d_in, const int* in_sizes, int n_in,
                              void* d_out, int out_size, void* d_ws, size_t ws_size,
                              hipStream_t stream) {
  const float* x    = (const float*)d_in[0];
  const float* adj1 = (const float*)d_in[1];
  const float* adj2 = (const float*)d_in[2];
  const float* W1   = (const float*)d_in[3];
  const float* b1   = (const float*)d_in[4];
  const float* W2   = (const float*)d_in[5];
  const float* b2   = (const float*)d_in[6];
  const float* aw   = (const float*)d_in[7];
  const float* cl   = (const float*)d_in[8];
  float* out = (float*)d_out;

  char* ws = (char*)d_ws;
  unsigned short* Yt1 = (unsigned short*)(ws + 0);        // 64*10240*2 = 1310720
  unsigned short* Yt2 = (unsigned short*)(ws + 1310720);
  unsigned short* Wt1 = (unsigned short*)(ws + 2621440);  // 64*512*2 = 65536
  unsigned short* Wt2 = (unsigned short*)(ws + 2686976);
  float* Ep           = (float*)(ws + 2752512);

  const size_t fixed = 2752512;
  const size_t per_split = 2ull * NROWS * NHID * 4ull;    // both branches: 5.12 MB
  const bool static_ok = ws_size >= fixed + (size_t)NSPLIT * per_split;

  hipMemsetAsync(Yt1, 0, 2 * 1310720, stream);
  prep_w<<<dim3(128), dim3(256), 0, stream>>>(W1, W2, Wt1, Wt2);
  gemm_xw<<<dim3(313), dim3(256), 0, stream>>>(x, Wt1, Wt2, Yt1, Yt2);

  if (static_ok) {
    gemm_adj<<<dim3(79, NSPLIT, 2), dim3(256), 0, stream>>>(adj1, adj2, Yt1, Yt2, Ep);
    fuse<<<dim3(2500), dim3(256), 0, stream>>>(Ep, NSPLIT, b1, b2, aw, cl, out);
  } else {
    int nsplit = 1;
    if (ws_size > fixed + per_split) {
      size_t s = (ws_size - fixed) / per_split;
      nsplit = (int)(s < 5 ? s : 5);
      if (nsplit < 1) nsplit = 1;
    }
    const int chunk = (KB_PAD + nsplit - 1) / nsplit;
    gemm_adj_dyn<<<dim3(157, nsplit, 2), dim3(256), 0, stream>>>(adj1, adj2, Yt1, Yt2,
                                                                 Ep, nsplit, chunk);
    fuse<<<dim3(2500), dim3(256), 0, stream>>>(Ep, nsplit, b1, b2, aw, cl, out);
  }
}

// Round 11
// 218.246 us; speedup vs baseline: 4.7039x; 1.0264x over previous
//
#include <hip/hip_runtime.h>
#include <math.h>

#define NROWS 10000
#define FEAT  512
#define NHID  64
#define NCLS  10
#define YT_STRIDE 10240   // 10000 padded (zeros in pad); stored XOR-swizzled
#define KB_PAD 320        // padded K blocks of 32 (for dyn fallback)
#define TK    64          // gemm_adj K-tile
#define TM    128         // gemm_adj M-tile
#define NSPLIT 5
#define NT    32          // tiles per split = 10240 / TK / NSPLIT

typedef __attribute__((ext_vector_type(8))) short short8;
typedef __attribute__((ext_vector_type(4))) short short4v;
typedef __attribute__((ext_vector_type(4))) float f32x4;

__device__ __forceinline__ short f2bf(float f) {
  union { float f; unsigned u; } v; v.f = f;
  unsigned r = v.u + 0x7fffu + ((v.u >> 16) & 1u);
  return (short)(r >> 16);
}

__device__ __forceinline__ float wsum64(float v) {
#pragma unroll
  for (int off = 32; off > 0; off >>= 1) v += __shfl_xor(v, off, 64);
  return v;
}

// async global->LDS, 16B per lane, LDS dest = wave-uniform base + lane*16.
__device__ __forceinline__ void gload16(const void* g, void* l) {
  __builtin_amdgcn_global_load_lds(
      (const __attribute__((address_space(1))) unsigned int*)g,
      (__attribute__((address_space(3))) unsigned int*)l, 16, 0, 0);
}

// ---------------------------------------------------------------------------
// Kernel 0: W transpose-convert for both branches PLUS Yt pad-zeroing (the
// pad positions q with (q ^ sw(col)) >= 10000 are never written by gemm_xw,
// so doing them here removes the hipMemsetAsync dispatch entirely).
__global__ __launch_bounds__(256) void prep_w(const float* __restrict__ W1,
                                              const float* __restrict__ W2,
                                              unsigned short* __restrict__ Wt1,
                                              unsigned short* __restrict__ Wt2,
                                              unsigned short* __restrict__ Yt1,
                                              unsigned short* __restrict__ Yt2) {
  int i = blockIdx.x * 256 + threadIdx.x;
  if (i < FEAT * NHID) {
    int k = i >> 6, h = i & 63;
    Wt1[h * FEAT + k] = (unsigned short)f2bf(W1[i]);
    Wt2[h * FEAT + k] = (unsigned short)f2bf(W2[i]);
  }
  // pad-zero: i encodes {br: bit14, col: bits 8-13, q-off: bits 0-7}
  {
    const int br  = i >> 14;
    const int col = (i >> 8) & 63;
    const int q   = 9984 + (i & 255);
    const int sw  = (col & 7) << 3;
    if ((q ^ sw) >= NROWS) {
      unsigned short* Yt = br ? Yt2 : Yt1;
      Yt[(size_t)col * YT_STRIDE + q] = 0;
    }
  }
}

// ---------------------------------------------------------------------------
// Kernel 1: Yt_b[col][row^sw(col)] = bf16((x @ W_b)[row][col]), sw(c)=(c&7)<<3.
// Epilogue packs 4 consecutive rows (sw flips only bits 3-5, so row0..row0+3
// map to consecutive swizzled positions) into one 8B store.
__global__ __launch_bounds__(256) void gemm_xw(const float* __restrict__ x,
                                               const unsigned short* __restrict__ Wt1,
                                               const unsigned short* __restrict__ Wt2,
                                               unsigned short* __restrict__ Yt1,
                                               unsigned short* __restrict__ Yt2) {
  const int lane = threadIdx.x & 63;
  const int wave = threadIdx.x >> 6;
  const int job = blockIdx.x * 4 + wave;
  if (job >= 1250) return;
  const int br = (job >= 625) ? 1 : 0;
  const int tile = job - 625 * br;
  const unsigned short* Wt = br ? Wt2 : Wt1;
  unsigned short* Yt       = br ? Yt2 : Yt1;
  const int rowbase = tile * 16;
  const int r16 = lane & 15, g = lane >> 4, ga = g * 8;

  const float* arow = x + (size_t)(rowbase + r16) * FEAT + ga;
  const unsigned short* bp = Wt + (size_t)r16 * FEAT + ga;

  f32x4 acc[4];
#pragma unroll
  for (int t = 0; t < 4; ++t) acc[t] = (f32x4){0.f, 0.f, 0.f, 0.f};

#pragma unroll
  for (int kb = 0; kb < FEAT / 32; ++kb) {
    const int k0 = kb * 32;
    const f32x4* ap = (const f32x4*)(arow + k0);
    f32x4 a0 = ap[0], a1 = ap[1];
    short8 af;
    af[0] = f2bf(a0[0]); af[1] = f2bf(a0[1]); af[2] = f2bf(a0[2]); af[3] = f2bf(a0[3]);
    af[4] = f2bf(a1[0]); af[5] = f2bf(a1[1]); af[6] = f2bf(a1[2]); af[7] = f2bf(a1[3]);
#pragma unroll
    for (int t = 0; t < 4; ++t) {
      short8 bf = *(const short8*)(bp + (size_t)t * 16 * FEAT + k0);
      acc[t] = __builtin_amdgcn_mfma_f32_16x16x32_bf16(af, bf, acc[t], 0, 0, 0);
    }
  }
  const int sw = (r16 & 7) << 3;           // col&7 == r16&7 (col = t*16+r16)
  const int row0 = rowbase + g * 4;        // multiple of 4; sw flips bits>=3
#pragma unroll
  for (int t = 0; t < 4; ++t) {
    const int col = t * 16 + r16;
    short4v p;
    p[0] = f2bf(acc[t][0]); p[1] = f2bf(acc[t][1]);
    p[2] = f2bf(acc[t][2]); p[3] = f2bf(acc[t][3]);
    *(short4v*)(Yt + (size_t)col * YT_STRIDE + (row0 ^ sw)) = p;
  }
}

// ---------------------------------------------------------------------------
// Kernel 2 (the hot one, unchanged from R10): E = adj @ Y.  TM=128 x 64 x
// TK=64 tile, A+B LDS ring via linear global_load_lds, D=2, vmcnt(10),
// LDS 80KB -> 2 blocks/CU.
__global__ __launch_bounds__(256, 2) void gemm_adj(const float* __restrict__ adj1,
                                                   const float* __restrict__ adj2,
                                                   const unsigned short* __restrict__ Yt1,
                                                   const unsigned short* __restrict__ Yt2,
                                                   float* __restrict__ Ep) {
  __shared__ __attribute__((aligned(16))) float          Asm[2][TM * TK];  // 2x32KB
  __shared__ __attribute__((aligned(16))) unsigned short Bsm[2][64 * TK];  // 2x8KB

  const int sp = blockIdx.y;
  const int br = blockIdx.z;
  const float* adj         = br ? adj2 : adj1;
  const unsigned short* Yt = br ? Yt2 : Yt1;
  float* E = Ep + (size_t)(br * NSPLIT + sp) * NROWS * NHID;
  const int k_base = sp * (NT * TK);
  const int blockrow = blockIdx.x * TM;

  const int lane = threadIdx.x & 63;
  const int wave = threadIdx.x >> 6;

  const int a_rt_l = lane >> 4;
  const int a_gran = (lane & 15) * 4;
  const int b_cl = lane >> 3;
  const int b_el = (lane & 7) * 8;

  const int r16 = lane & 15, g = lane >> 4;
  const int aswz = (r16 & 7) << 2;
  const int swb  = (r16 & 7) << 3;

  f32x4 acc0[4], acc1[4];
#pragma unroll
  for (int t = 0; t < 4; ++t) {
    acc0[t] = (f32x4){0.f, 0.f, 0.f, 0.f};
    acc1[t] = (f32x4){0.f, 0.f, 0.f, 0.f};
  }

#define STAGE(tt) { const int k0s = k_base + (tt) * TK; const int bufs = (tt) & 1;   \
    _Pragma("unroll")                                                                 \
    for (int j = 0; j < 8; ++j) {                                                     \
      const int rtb = wave * 32 + j * 4;                                              \
      const int rt = rtb + a_rt_l;                                                    \
      const int gr = min(blockrow + rt, NROWS - 1);                                   \
      const int fsrc = a_gran ^ ((rt & 7) << 2);                                      \
      const float* asrc = adj + (size_t)gr * NROWS + min(k0s + fsrc, NROWS - 4);      \
      gload16(asrc, &Asm[bufs][rtb * TK]);                                            \
    }                                                                                 \
    _Pragma("unroll")                                                                 \
    for (int j = 0; j < 2; ++j) {                                                     \
      const int c0 = wave * 16 + j * 8;                                               \
      const unsigned short* bsrc =                                                    \
          Yt + (size_t)(c0 + b_cl) * YT_STRIDE + (k0s + b_el);                        \
      gload16(bsrc, &Bsm[bufs][c0 * TK]);                                             \
    } }

#define COMPUTE(tt) { const int bufc = (tt) & 1;                                      \
    const float* ab0 = &Asm[bufc][(wave * 32 + r16) * TK];                            \
    const float* ab1 = &Asm[bufc][(wave * 32 + 16 + r16) * TK];                       \
    _Pragma("unroll")                                                                 \
    for (int ks = 0; ks < 2; ++ks) {                                                  \
      const int kx = ks * 32 + g * 8;                                                 \
      f32x4 a00 = *(const f32x4*)(ab0 + (kx ^ aswz));                                 \
      f32x4 a01 = *(const f32x4*)(ab0 + ((kx + 4) ^ aswz));                           \
      f32x4 a10 = *(const f32x4*)(ab1 + (kx ^ aswz));                                 \
      f32x4 a11 = *(const f32x4*)(ab1 + ((kx + 4) ^ aswz));                           \
      short8 af0, af1;                                                                \
      af0[0] = f2bf(a00[0]); af0[1] = f2bf(a00[1]); af0[2] = f2bf(a00[2]);            \
      af0[3] = f2bf(a00[3]); af0[4] = f2bf(a01[0]); af0[5] = f2bf(a01[1]);            \
      af0[6] = f2bf(a01[2]); af0[7] = f2bf(a01[3]);                                   \
      af1[0] = f2bf(a10[0]); af1[1] = f2bf(a10[1]); af1[2] = f2bf(a10[2]);            \
      af1[3] = f2bf(a10[3]); af1[4] = f2bf(a11[0]); af1[5] = f2bf(a11[1]);            \
      af1[6] = f2bf(a11[2]); af1[7] = f2bf(a11[3]);                                   \
      _Pragma("unroll")                                                               \
      for (int ct = 0; ct < 4; ++ct) {                                                \
        short8 b = *(const short8*)&Bsm[bufc][(ct * 16 + r16) * TK + (kx ^ swb)];     \
        acc0[ct] = __builtin_amdgcn_mfma_f32_16x16x32_bf16(af0, b, acc0[ct], 0, 0, 0);\
        acc1[ct] = __builtin_amdgcn_mfma_f32_16x16x32_bf16(af1, b, acc1[ct], 0, 0, 0);\
      }                                                                               \
    } }

  STAGE(0);
#pragma unroll 2
  for (int t = 0; t < NT - 1; ++t) {
    STAGE(t + 1);
    asm volatile("s_waitcnt vmcnt(10)" ::: "memory");  // tile t landed; t+1 flying
    __builtin_amdgcn_sched_barrier(0);
    __builtin_amdgcn_s_barrier();
    __builtin_amdgcn_sched_barrier(0);
    COMPUTE(t);
    __builtin_amdgcn_s_barrier();
  }
  asm volatile("s_waitcnt vmcnt(0)" ::: "memory");
  __builtin_amdgcn_sched_barrier(0);
  __builtin_amdgcn_s_barrier();
  __builtin_amdgcn_sched_barrier(0);
  COMPUTE(NT - 1);
#undef STAGE
#undef COMPUTE

#pragma unroll
  for (int ct = 0; ct < 4; ++ct)
#pragma unroll
    for (int rr = 0; rr < 4; ++rr) {
      const int grow0 = blockrow + wave * 32 + g * 4 + rr;
      const int grow1 = grow0 + 16;
      const int col   = ct * 16 + r16;
      if (grow0 < NROWS) E[(size_t)grow0 * NHID + col] = acc0[ct][rr];
      if (grow1 < NROWS) E[(size_t)grow1 * NHID + col] = acc1[ct][rr];
    }
}

// ---------------------------------------------------------------------------
// Fallback (dynamic split) if workspace is tight.  Swizzle-aware B reads.
__global__ __launch_bounds__(256) void gemm_adj_dyn(const float* __restrict__ adj1,
                                                    const float* __restrict__ adj2,
                                                    const unsigned short* __restrict__ Yt1,
                                                    const unsigned short* __restrict__ Yt2,
                                                    float* __restrict__ Ep,
                                                    int nsplit, int chunk) {
  const int sp = blockIdx.y;
  const int br = blockIdx.z;
  const float* adj          = br ? adj2 : adj1;
  const unsigned short* Yt  = br ? Yt2 : Yt1;
  float* E = Ep + (size_t)(br * nsplit + sp) * NROWS * NHID;

  const int kb_begin = sp * chunk;
  const int kb_end   = min(kb_begin + chunk, KB_PAD);

  const int lane = threadIdx.x & 63;
  const int wave = threadIdx.x >> 6;
  const int rowbase = blockIdx.x * 64 + wave * 16;
  if (rowbase >= NROWS) return;
  const int r = lane & 15;
  const int g = lane >> 4;
  const int ga = g * 8;
  const int sw = (r & 7) << 3;

  const float* arow = adj + (size_t)(rowbase + r) * NROWS;

  f32x4 acc0 = (f32x4){0.f, 0.f, 0.f, 0.f};
  f32x4 acc1 = acc0, acc2 = acc0, acc3 = acc0;

#pragma unroll 4
  for (int kb = kb_begin; kb < kb_end; ++kb) {
    const int k0 = kb * 32;
    const int kc = min(k0 + ga, 9992);
    const int ks = (k0 + ga) ^ sw;
    const f32x4* ap = (const f32x4*)(arow + kc);
    f32x4 a0 = ap[0], a1 = ap[1];
    short8 af;
    af[0] = f2bf(a0[0]); af[1] = f2bf(a0[1]); af[2] = f2bf(a0[2]); af[3] = f2bf(a0[3]);
    af[4] = f2bf(a1[0]); af[5] = f2bf(a1[1]); af[6] = f2bf(a1[2]); af[7] = f2bf(a1[3]);
    short8 bf0 = *(const short8*)(Yt + (size_t)(0 * 16 + r) * YT_STRIDE + ks);
    short8 bf1 = *(const short8*)(Yt + (size_t)(1 * 16 + r) * YT_STRIDE + ks);
    short8 bf2 = *(const short8*)(Yt + (size_t)(2 * 16 + r) * YT_STRIDE + ks);
    short8 bf3 = *(const short8*)(Yt + (size_t)(3 * 16 + r) * YT_STRIDE + ks);
    acc0 = __builtin_amdgcn_mfma_f32_16x16x32_bf16(af, bf0, acc0, 0, 0, 0);
    acc1 = __builtin_amdgcn_mfma_f32_16x16x32_bf16(af, bf1, acc1, 0, 0, 0);
    acc2 = __builtin_amdgcn_mfma_f32_16x16x32_bf16(af, bf2, acc2, 0, 0, 0);
    acc3 = __builtin_amdgcn_mfma_f32_16x16x32_bf16(af, bf3, acc3, 0, 0, 0);
  }

  const size_t ebase = (size_t)(rowbase + g * 4) * NHID + r;
#pragma unroll
  for (int rr = 0; rr < 4; ++rr) {
    E[ebase + (size_t)rr * NHID +  0] = acc0[rr];
    E[ebase + (size_t)rr * NHID + 16] = acc1[rr];
    E[ebase + (size_t)rr * NHID + 32] = acc2[rr];
    E[ebase + (size_t)rr * NHID + 48] = acc3[rr];
  }
}

// ---------------------------------------------------------------------------
// Kernel 3: split-K reduction + bias + attention fusion + DEC assignment.
__global__ __launch_bounds__(256) void fuse(const float* __restrict__ Ep,
                                            int nsplit,
                                            const float* __restrict__ b1,
                                            const float* __restrict__ b2,
                                            const float* __restrict__ aw,
                                            const float* __restrict__ cl,
                                            float* __restrict__ out) {
  const int lane = threadIdx.x & 63;
  const int wave = threadIdx.x >> 6;
  const int row = blockIdx.x * 4 + wave;
  if (row >= NROWS) return;

  const size_t off = (size_t)row * NHID + lane;
  const size_t bstride = (size_t)nsplit * NROWS * NHID;
  float e1 = b1[lane], e2 = b2[lane];
  for (int s = 0; s < nsplit; ++s) {
    e1 += Ep[(size_t)s * NROWS * NHID + off];
    e2 += Ep[bstride + (size_t)s * NROWS * NHID + off];
  }

  float a = aw[lane];
  float w1 = wsum64(e1 * a);
  float w2 = wsum64(e2 * a);
  float m = fmaxf(w1, w2);
  float x1 = expf(w1 - m), x2 = expf(w2 - m);
  float inv = 1.0f / (x1 + x2);
  float emb = (x1 * e1 + x2 * e2) * inv;
  out[off] = emb;

  float myq = 0.f, qs = 0.f;
#pragma unroll
  for (int c = 0; c < NCLS; ++c) {
    float d = emb - cl[c * NHID + lane];
    float s = wsum64(d * d);
    float t = exp2f(-0.72f * log2f(fmaf(5.0f, s, 1.0f)));
    qs += t;
    if (lane == c) myq = t;
  }
  if (lane < NCLS) out[(size_t)NROWS * NHID + (size_t)row * NCLS + lane] = myq / qs;
}

// ---------------------------------------------------------------------------
extern "C" void kernel_launch(void* const* d_in, const int* in_sizes, int n_in,
                              void* d_out, int out_size, void* d_ws, size_t ws_size,
                              hipStream_t stream) {
  const float* x    = (const float*)d_in[0];
  const float* adj1 = (const float*)d_in[1];
  const float* adj2 = (const float*)d_in[2];
  const float* W1   = (const float*)d_in[3];
  const float* b1   = (const float*)d_in[4];
  const float* W2   = (const float*)d_in[5];
  const float* b2   = (const float*)d_in[6];
  const float* aw   = (const float*)d_in[7];
  const float* cl   = (const float*)d_in[8];
  float* out = (float*)d_out;

  char* ws = (char*)d_ws;
  unsigned short* Yt1 = (unsigned short*)(ws + 0);        // 64*10240*2 = 1310720
  unsigned short* Yt2 = (unsigned short*)(ws + 1310720);
  unsigned short* Wt1 = (unsigned short*)(ws + 2621440);  // 64*512*2 = 65536
  unsigned short* Wt2 = (unsigned short*)(ws + 2686976);
  float* Ep           = (float*)(ws + 2752512);

  const size_t fixed = 2752512;
  const size_t per_split = 2ull * NROWS * NHID * 4ull;    // both branches: 5.12 MB
  const bool static_ok = ws_size >= fixed + (size_t)NSPLIT * per_split;

  prep_w<<<dim3(128), dim3(256), 0, stream>>>(W1, W2, Wt1, Wt2, Yt1, Yt2);
  gemm_xw<<<dim3(313), dim3(256), 0, stream>>>(x, Wt1, Wt2, Yt1, Yt2);

  if (static_ok) {
    gemm_adj<<<dim3(79, NSPLIT, 2), dim3(256), 0, stream>>>(adj1, adj2, Yt1, Yt2, Ep);
    fuse<<<dim3(2500), dim3(256), 0, stream>>>(Ep, NSPLIT, b1, b2, aw, cl, out);
  } else {
    int nsplit = 1;
    if (ws_size > fixed + per_split) {
      size_t s = (ws_size - fixed) / per_split;
      nsplit = (int)(s < 5 ? s : 5);
      if (nsplit < 1) nsplit = 1;
    }
    const int chunk = (KB_PAD + nsplit - 1) / nsplit;
    gemm_adj_dyn<<<dim3(157, nsplit, 2), dim3(256), 0, stream>>>(adj1, adj2, Yt1, Yt2,
                                                                 Ep, nsplit, chunk);
    fuse<<<dim3(2500), dim3(256), 0, stream>>>(Ep, nsplit, b1, b2, aw, cl, out);
  }
}